// Round 1
// baseline (776.706 us; speedup 1.0000x reference)
//
#include <hip/hip_runtime.h>
#include <float.h>
#include <math.h>

// NPairLoss on MI355X. B=8192 rows, D=256 dims, C=100 classes.
// Pipeline: sq_kernel -> fused_kernel (tiled gram + online lse + threefry gumbel argmax,
// j-range split 8 ways) -> combine_kernel (merge partials per row) -> reduce_kernel (loss).
// ws usage: ~1.35 MB.

#define B_N 8192
#define D_K 256
#define TI 64
#define TJ 64
#define TK 64
#define NSPLIT 8
#define JRANGE (B_N / NSPLIT)   // 1024
#define NJT (JRANGE / TJ)       // 16
#define NKC (D_K / TK)          // 4
#define LPAD 68                 // padded LDS stride (floats): keeps 16B alignment for b128 reads

// ---------------- threefry2x32 / jax gumbel ----------------
__device__ __forceinline__ unsigned rotl32(unsigned x, int d){ return (x << d) | (x >> (32 - d)); }

// Reproduces jax.random.gumbel(jax.random.key(42), (B,B), f32)[i,j] at flat idx = i*B + j.
// jax random_bits: bits = threefry_2x32(key=[0,42], iota(B*B)); counts split in halves:
// out[idx<H] = hash(idx, idx+H).x0 ; out[idx>=H] = hash(idx-H, idx).x1, H = B*B/2.
__device__ __forceinline__ float gumbel_at(unsigned idx){
  const unsigned HALF = (unsigned)B_N * (unsigned)B_N / 2u; // 33554432
  unsigned c0, c1; bool second;
  if (idx < HALF){ c0 = idx; c1 = idx + HALF; second = false; }
  else            { c0 = idx - HALF; c1 = idx; second = true; }
  const unsigned ks0 = 0u, ks1 = 42u, ks2 = 0u ^ 42u ^ 0x1BD11BDAu;
  unsigned x0 = c0 + ks0, x1 = c1 + ks1;
#define TF_RND(r) { x0 += x1; x1 = rotl32(x1, (r)); x1 ^= x0; }
  TF_RND(13) TF_RND(15) TF_RND(26) TF_RND(6)   x0 += ks1; x1 += ks2 + 1u;
  TF_RND(17) TF_RND(29) TF_RND(16) TF_RND(24)  x0 += ks2; x1 += ks0 + 2u;
  TF_RND(13) TF_RND(15) TF_RND(26) TF_RND(6)   x0 += ks0; x1 += ks1 + 3u;
  TF_RND(17) TF_RND(29) TF_RND(16) TF_RND(24)  x0 += ks1; x1 += ks2 + 4u;
  TF_RND(13) TF_RND(15) TF_RND(26) TF_RND(6)   x0 += ks2; x1 += ks0 + 5u;
#undef TF_RND
  unsigned bits = second ? x1 : x0;
  // jax _uniform: u = bitcast((bits>>9)|0x3f800000) - 1 ; u = u*(1-tiny)+tiny ; u = max(tiny,u)
  float u = __uint_as_float((bits >> 9) | 0x3f800000u) - 1.0f;
  const float TINY = 1.17549435e-38f;
  u = u * (1.0f - TINY) + TINY;
  u = fmaxf(TINY, u);
  return -logf(-logf(u));
}

// ---------------- kernels ----------------
__global__ void sq_kernel(const float* __restrict__ E, float* __restrict__ sq){
  int row = blockIdx.x;
  int lane = threadIdx.x; // 64
  const float4 v = *reinterpret_cast<const float4*>(E + (size_t)row * D_K + lane * 4);
  float s = v.x*v.x + v.y*v.y + v.z*v.z + v.w*v.w;
#pragma unroll
  for (int off = 32; off > 0; off >>= 1) s += __shfl_down(s, off);
  if (lane == 0) sq[row] = s;
}

__global__ __launch_bounds__(256, 4)
void fused_kernel(const float* __restrict__ E, const int* __restrict__ labels,
                  const float* __restrict__ sq,
                  float* __restrict__ wsM, float* __restrict__ wsS,
                  float* __restrict__ wsG, float* __restrict__ wsSB,
                  unsigned* __restrict__ wsF)
{
  __shared__ __align__(16) float At[TK][LPAD]; // At[k][i] = E[i0+i][k0+k]
  __shared__ __align__(16) float Bt[TK][LPAD]; // Bt[k][j] = E[j0+j][k0+k]

  const int bi    = blockIdx.x / NSPLIT;
  const int split = blockIdx.x % NSPLIT;
  const int i0    = bi * TI;
  const int jbase = split * JRANGE;
  const int tid   = threadIdx.x;
  const int tx    = tid & 15;   // j micro position (16 groups of 4)
  const int ty    = tid >> 4;   // i micro position (16 groups of 4)

  int gi[4]; float sqi[4]; int li[4];
#pragma unroll
  for (int ii = 0; ii < 4; ii++){
    gi[ii]  = i0 + (ty << 2) + ii;
    sqi[ii] = sq[gi[ii]];
    li[ii]  = labels[gi[ii]];
  }

  // per-(thread,row) state over this thread's j-subset
  float m[4], s[4], gmax[4], simb[4];
  bool hp[4], hn[4];
#pragma unroll
  for (int ii = 0; ii < 4; ii++){
    m[ii] = -FLT_MAX; s[ii] = 0.f; gmax[ii] = -FLT_MAX; simb[ii] = 0.f;
    hp[ii] = false; hn[ii] = false;
  }

  for (int jt = 0; jt < NJT; jt++){
    const int j0 = jbase + jt * TJ;
    float acc[4][4];
#pragma unroll
    for (int ii = 0; ii < 4; ii++)
#pragma unroll
      for (int jj = 0; jj < 4; jj++) acc[ii][jj] = 0.f;

    for (int kc = 0; kc < NKC; kc++){
      const int k0 = kc * TK;
      __syncthreads(); // previous tile consumers done
#pragma unroll
      for (int l = 0; l < 4; l++){
        int t    = tid + l * 256;      // 0..1023
        int row  = t >> 4;             // 0..63
        int col4 = (t & 15) << 2;      // 0,4,...,60
        float4 va = *reinterpret_cast<const float4*>(E + (size_t)(i0 + row) * D_K + k0 + col4);
        At[col4+0][row] = va.x; At[col4+1][row] = va.y; At[col4+2][row] = va.z; At[col4+3][row] = va.w;
        float4 vb = *reinterpret_cast<const float4*>(E + (size_t)(j0 + row) * D_K + k0 + col4);
        Bt[col4+0][row] = vb.x; Bt[col4+1][row] = vb.y; Bt[col4+2][row] = vb.z; Bt[col4+3][row] = vb.w;
      }
      __syncthreads();
#pragma unroll 8
      for (int k = 0; k < TK; k++){
        float4 a = *reinterpret_cast<const float4*>(&At[k][ty << 2]);
        float4 b = *reinterpret_cast<const float4*>(&Bt[k][tx << 2]);
        acc[0][0] += a.x*b.x; acc[0][1] += a.x*b.y; acc[0][2] += a.x*b.z; acc[0][3] += a.x*b.w;
        acc[1][0] += a.y*b.x; acc[1][1] += a.y*b.y; acc[1][2] += a.y*b.z; acc[1][3] += a.y*b.w;
        acc[2][0] += a.z*b.x; acc[2][1] += a.z*b.y; acc[2][2] += a.z*b.z; acc[2][3] += a.z*b.w;
        acc[3][0] += a.w*b.x; acc[3][1] += a.w*b.y; acc[3][2] += a.w*b.z; acc[3][3] += a.w*b.w;
      }
    }

    // epilogue for this 64x64 tile
    int gj[4]; float sqj[4]; int lj[4];
#pragma unroll
    for (int jj = 0; jj < 4; jj++){
      gj[jj]  = j0 + (tx << 2) + jj;
      sqj[jj] = sq[gj[jj]];
      lj[jj]  = labels[gj[jj]];
    }
#pragma unroll
    for (int ii = 0; ii < 4; ii++){
#pragma unroll
      for (int jj = 0; jj < 4; jj++){
        float d2   = fmaxf(sqi[ii] + sqj[jj] - 2.0f * acc[ii][jj], 0.0f);
        float simv = -d2 * 10.0f; // /TEMPERATURE
        if (li[ii] != lj[jj]){
          // negative: online logsumexp (diag is same-label, auto-excluded)
          float M = fmaxf(m[ii], simv);
          s[ii] = s[ii] * expf(m[ii] - M) + expf(simv - M);
          m[ii] = M;
          hn[ii] = true;
        } else if (gi[ii] != gj[jj]){
          // positive: gumbel argmax, keep winning sim
          float g = gumbel_at(((unsigned)gi[ii] << 13) + (unsigned)gj[jj]);
          if (g > gmax[ii]){ gmax[ii] = g; simb[ii] = simv; }
          hp[ii] = true;
        }
      }
    }
  }

  // merge across the 16 tx-lanes sharing each row (lane bits 0..3 == tx)
#pragma unroll
  for (int ii = 0; ii < 4; ii++){
    float mv = m[ii], sv = s[ii], gv = gmax[ii], sbv = simb[ii];
    unsigned fl = (hp[ii] ? 1u : 0u) | (hn[ii] ? 2u : 0u);
    for (int mask = 1; mask < 16; mask <<= 1){
      float m2  = __shfl_xor(mv, mask);
      float s2  = __shfl_xor(sv, mask);
      float g2  = __shfl_xor(gv, mask);
      float sb2 = __shfl_xor(sbv, mask);
      unsigned f2 = __shfl_xor(fl, mask);
      float M = fmaxf(mv, m2);
      sv = sv * expf(mv - M) + s2 * expf(m2 - M);
      mv = M;
      if (g2 > gv){ gv = g2; sbv = sb2; }
      fl |= f2;
    }
    if (tx == 0){
      int o = split * B_N + i0 + (ty << 2) + ii;
      wsM[o] = mv; wsS[o] = sv; wsG[o] = gv; wsSB[o] = sbv; wsF[o] = fl;
    }
  }
}

__global__ void combine_kernel(const float* __restrict__ wsM, const float* __restrict__ wsS,
                               const float* __restrict__ wsG, const float* __restrict__ wsSB,
                               const unsigned* __restrict__ wsF,
                               float* __restrict__ per_row, unsigned* __restrict__ valid)
{
  int row = blockIdx.x * blockDim.x + threadIdx.x;
  if (row >= B_N) return;
  float m = -FLT_MAX, s = 0.f, g = -FLT_MAX, sb = 0.f; unsigned fl = 0u;
  for (int p = 0; p < NSPLIT; p++){
    int o = p * B_N + row;
    float m2 = wsM[o], s2 = wsS[o], g2 = wsG[o], sb2 = wsSB[o];
    unsigned f2 = wsF[o];
    float M = fmaxf(m, m2);
    s = s * expf(m - M) + s2 * expf(m2 - M);
    m = M;
    if ((f2 & 1u) && g2 > g){ g = g2; sb = sb2; }
    fl |= f2;
  }
  bool v = ((fl & 1u) != 0u) && ((fl & 2u) != 0u);
  float den = m + logf(s);     // logsumexp over negatives (== ref with -1e30 sentinel)
  per_row[row] = v ? (den - sb) : 0.f;  // -(num - den)
  valid[row]   = v ? 1u : 0u;
}

__global__ void reduce_kernel(const float* __restrict__ per_row, const unsigned* __restrict__ valid,
                              float* __restrict__ out)
{
  int tid = threadIdx.x;
  float s = 0.f; unsigned n = 0u;
  for (int r = tid; r < B_N; r += 256){ s += per_row[r]; n += valid[r]; }
#pragma unroll
  for (int off = 32; off > 0; off >>= 1){ s += __shfl_down(s, off); n += __shfl_down(n, off); }
  __shared__ float ss[4]; __shared__ unsigned sn[4];
  if ((tid & 63) == 0){ ss[tid >> 6] = s; sn[tid >> 6] = n; }
  __syncthreads();
  if (tid == 0){
    float S = ss[0] + ss[1] + ss[2] + ss[3];
    unsigned N = sn[0] + sn[1] + sn[2] + sn[3];
    out[0] = (N > 0u) ? (S / (float)N) : 0.f;
  }
}

extern "C" void kernel_launch(void* const* d_in, const int* in_sizes, int n_in,
                              void* d_out, int out_size, void* d_ws, size_t ws_size,
                              hipStream_t stream)
{
  const float* E      = (const float*)d_in[0];
  const int*   labels = (const int*)d_in[1];
  float*       out    = (float*)d_out;

  // workspace layout (assumes ws_size >= ~1.4 MB)
  float*    wsM     = (float*)d_ws;
  float*    wsS     = wsM  + NSPLIT * B_N;
  float*    wsG     = wsS  + NSPLIT * B_N;
  float*    wsSB    = wsG  + NSPLIT * B_N;
  unsigned* wsF     = (unsigned*)(wsSB + NSPLIT * B_N);
  float*    sqbuf   = (float*)(wsF + NSPLIT * B_N);
  float*    per_row = sqbuf + B_N;
  unsigned* valid   = (unsigned*)(per_row + B_N);

  sq_kernel<<<B_N, 64, 0, stream>>>(E, sqbuf);
  fused_kernel<<<(B_N / TI) * NSPLIT, 256, 0, stream>>>(E, labels, sqbuf, wsM, wsS, wsG, wsSB, wsF);
  combine_kernel<<<B_N / 256, 256, 0, stream>>>(wsM, wsS, wsG, wsSB, wsF, per_row, valid);
  reduce_kernel<<<1, 256, 0, stream>>>(per_row, valid, out);
}

// Round 2
// 269.046 us; speedup vs baseline: 2.8869x; 2.8869x over previous
//
#include <hip/hip_runtime.h>
#include <float.h>
#include <math.h>

// NPairLoss MI355X r2: bf16 MFMA gram + precomputed gumbel selection.
// prep(convert+sq) -> sel(threefry argmax per row) -> fused(MFMA + masked-lse epilogue,
// j split 8 ways) -> combine -> reduce.  ws: ~4.9 MB.

#define B_N 8192
#define D_K 256
#define NSPLIT 8
#define JR (B_N / NSPLIT)      // 1024
#define BI 128
#define BJ 128
#define NJT (JR / BJ)          // 8
#define BK 64
#define NKC (D_K / BK)         // 4
#define NEG_INF -1e30f

typedef __attribute__((ext_vector_type(8))) short bf16x8;
typedef __attribute__((ext_vector_type(4))) float f32x4;
typedef unsigned short ushort_t;

// ---------------- threefry2x32 / jax gumbel (identical to r1 — known-good) ----------------
__device__ __forceinline__ unsigned rotl32(unsigned x, int d){ return (x << d) | (x >> (32 - d)); }

__device__ __forceinline__ float gumbel_at(unsigned idx){
  const unsigned HALF = (unsigned)B_N * (unsigned)B_N / 2u;
  unsigned c0, c1; bool second;
  if (idx < HALF){ c0 = idx; c1 = idx + HALF; second = false; }
  else            { c0 = idx - HALF; c1 = idx; second = true; }
  const unsigned ks0 = 0u, ks1 = 42u, ks2 = 0u ^ 42u ^ 0x1BD11BDAu;
  unsigned x0 = c0 + ks0, x1 = c1 + ks1;
#define TF_RND(r) { x0 += x1; x1 = rotl32(x1, (r)); x1 ^= x0; }
  TF_RND(13) TF_RND(15) TF_RND(26) TF_RND(6)   x0 += ks1; x1 += ks2 + 1u;
  TF_RND(17) TF_RND(29) TF_RND(16) TF_RND(24)  x0 += ks2; x1 += ks0 + 2u;
  TF_RND(13) TF_RND(15) TF_RND(26) TF_RND(6)   x0 += ks0; x1 += ks1 + 3u;
  TF_RND(17) TF_RND(29) TF_RND(16) TF_RND(24)  x0 += ks1; x1 += ks2 + 4u;
  TF_RND(13) TF_RND(15) TF_RND(26) TF_RND(6)   x0 += ks2; x1 += ks0 + 5u;
#undef TF_RND
  unsigned bits = second ? x1 : x0;
  float u = __uint_as_float((bits >> 9) | 0x3f800000u) - 1.0f;
  const float TINY = 1.17549435e-38f;
  u = u * (1.0f - TINY) + TINY;
  u = fmaxf(TINY, u);
  return -logf(-logf(u));
}

__device__ __forceinline__ ushort_t f2bf(float x){
  unsigned u = __float_as_uint(x);
  return (ushort_t)((u + 0x7FFFu + ((u >> 16) & 1u)) >> 16); // RNE
}

__device__ __forceinline__ void async16(const ushort_t* g, ushort_t* lds_wave_base){
  __builtin_amdgcn_global_load_lds((const __attribute__((address_space(1))) void*)g,
                                   (__attribute__((address_space(3))) void*)lds_wave_base,
                                   16, 0, 0);
}

// ---------------- prep: E fp32 -> Ebf bf16, sq[i] = ||E_i||^2 (exact fp32) ----------------
__global__ void prep_kernel(const float* __restrict__ E, ushort_t* __restrict__ Ebf,
                            float* __restrict__ sq){
  int w = threadIdx.x >> 6, lane = threadIdx.x & 63;
  int row = blockIdx.x * 4 + w;
  const float4 v = *reinterpret_cast<const float4*>(E + (size_t)row * D_K + lane * 4);
  float s = v.x*v.x + v.y*v.y + v.z*v.z + v.w*v.w;
#pragma unroll
  for (int off = 32; off > 0; off >>= 1) s += __shfl_down(s, off);
  if (lane == 0) sq[row] = s;
  ushort4 o; o.x = f2bf(v.x); o.y = f2bf(v.y); o.z = f2bf(v.z); o.w = f2bf(v.w);
  *reinterpret_cast<ushort4*>(Ebf + (size_t)row * D_K + lane * 4) = o;
}

// ---------------- sel: per-row gumbel-argmax positive (labels-only) ----------------
__global__ void sel_kernel(const int* __restrict__ labels, int* __restrict__ jsel,
                           float* __restrict__ numer){
  __shared__ int s_lab[B_N];
  int tid = threadIdx.x;
  for (int t = tid; t < B_N; t += 256) s_lab[t] = labels[t];
  __syncthreads();
  int w = tid >> 6, lane = tid & 63;
  int row = blockIdx.x * 4 + w;
  int li = s_lab[row];
  float gb = -FLT_MAX; int jb = 0x7FFFFFFF;
  for (int j = lane; j < B_N; j += 64){
    if (j != row && s_lab[j] == li){
      float g = gumbel_at(((unsigned)row << 13) + (unsigned)j);
      if (g > gb){ gb = g; jb = j; }  // ascending j per lane => first-max kept on ties
    }
  }
#pragma unroll
  for (int mask = 1; mask < 64; mask <<= 1){
    float g2 = __shfl_xor(gb, mask);
    int   j2 = __shfl_xor(jb, mask);
    if (g2 > gb || (g2 == gb && j2 < jb)){ gb = g2; jb = j2; }
  }
  if (lane == 0){ jsel[row] = (jb != 0x7FFFFFFF) ? jb : -1; numer[row] = 0.f; }
}

// ---------------- fused: MFMA gram tile + masked online-lse epilogue ----------------
__global__ __launch_bounds__(256, 3)
void fused_kernel(const ushort_t* __restrict__ Ebf, const int* __restrict__ labels,
                  const float* __restrict__ sq, const int* __restrict__ jsel,
                  float* __restrict__ numer,
                  float* __restrict__ wsM, float* __restrict__ wsS)
{
  __shared__ __align__(16) ushort_t As[BI * BK];  // XOR-swizzled 16B groups
  __shared__ __align__(16) ushort_t Bs[BJ * BK];
  __shared__ float s_sqj[JR];
  __shared__ int   s_lj[JR];
  __shared__ float s_sqi[BI];
  __shared__ int   s_li[BI];
  __shared__ int   s_ji[BI];

  const int bi    = blockIdx.x >> 3;
  const int split = blockIdx.x & 7;
  const int i0    = bi * BI;
  const int jbase = split * JR;
  const int tid   = threadIdx.x;
  const int lane  = tid & 63;
  const int w     = tid >> 6;
  const int quad  = lane >> 4;
  const int l15   = lane & 15;

  for (int t = tid; t < JR; t += 256){ s_sqj[t] = sq[jbase + t]; s_lj[t] = labels[jbase + t]; }
  if (tid < BI){ s_sqi[tid] = sq[i0 + tid]; s_li[tid] = labels[i0 + tid]; s_ji[tid] = jsel[i0 + tid]; }

  float sm[8], ss[8];
#pragma unroll
  for (int r = 0; r < 8; r++){ sm[r] = NEG_INF; ss[r] = 0.f; }

  for (int jt = 0; jt < NJT; jt++){
    const int j0 = jbase + jt * BJ;
    f32x4 acc[2][8];
#pragma unroll
    for (int mt = 0; mt < 2; mt++)
#pragma unroll
      for (int nt = 0; nt < 8; nt++) acc[mt][nt] = (f32x4)0.f;

    for (int kc = 0; kc < NKC; kc++){
      const int koff = kc * BK;
#pragma unroll
      for (int rd = 0; rd < 4; rd++){
        int slot = rd * 256 + tid;            // 16B slot: row = slot>>3, group = slot&7
        int r = slot >> 3, gs = slot & 7;
        int gsrc = (gs ^ (r & 7)) << 3;       // source k-offset (elements) — swizzle on gather side
        ushort_t* ldsA = As + (size_t)(rd * 256 + w * 64) * 8;  // wave-uniform base
        ushort_t* ldsB = Bs + (size_t)(rd * 256 + w * 64) * 8;
        async16(Ebf + (size_t)(i0 + r) * D_K + koff + gsrc, ldsA);
        async16(Ebf + (size_t)(j0 + r) * D_K + koff + gsrc, ldsB);
      }
      __syncthreads();                         // loads drained (vmcnt 0 before s_barrier)
#pragma unroll
      for (int s = 0; s < 2; s++){
        bf16x8 af[2], bfr[8];
        int g = s * 4 + quad;                  // logical 8-elem k-group within 64-chunk
#pragma unroll
        for (int mt = 0; mt < 2; mt++){
          int r = w * 32 + mt * 16 + l15;
          af[mt] = *reinterpret_cast<const bf16x8*>(&As[r * BK + ((g ^ (r & 7)) << 3)]);
        }
#pragma unroll
        for (int nt = 0; nt < 8; nt++){
          int r = nt * 16 + l15;
          bfr[nt] = *reinterpret_cast<const bf16x8*>(&Bs[r * BK + ((g ^ (r & 7)) << 3)]);
        }
#pragma unroll
        for (int mt = 0; mt < 2; mt++)
#pragma unroll
          for (int nt = 0; nt < 8; nt++)
            acc[mt][nt] = __builtin_amdgcn_mfma_f32_16x16x32_bf16(af[mt], bfr[nt], acc[mt][nt], 0, 0, 0);
      }
      __syncthreads();                         // protect LDS before next staging
    }

    // ---- epilogue for this 128x128 tile ----
    float sqj[8]; int lj[8];
#pragma unroll
    for (int nt = 0; nt < 8; nt++){
      int c = jt * BJ + nt * 16 + l15;
      sqj[nt] = s_sqj[c]; lj[nt] = s_lj[c];
    }
#pragma unroll
    for (int mt = 0; mt < 2; mt++){
#pragma unroll
      for (int rr = 0; rr < 4; rr++){
        int rl = w * 32 + mt * 16 + quad * 4 + rr;   // C/D: row = quad*4+reg, col = l15
        float sqv = s_sqi[rl]; int lrow = s_li[rl]; int jsl = s_ji[rl];
        int sidx = mt * 4 + rr;
        float sv[8];
#pragma unroll
        for (int nt = 0; nt < 8; nt++){
          float a = acc[mt][nt][rr];
          float simv = -10.f * fmaxf(fmaf(-2.f, a, sqv + sqj[nt]), 0.f);
          int colg = j0 + nt * 16 + l15;
          if (colg == jsl) numer[i0 + rl] = simv;    // rare predicated store (numerator)
          sv[nt] = (lj[nt] != lrow) ? simv : NEG_INF; // mask positives + same-label + diag
        }
        float m8 = fmaxf(fmaxf(fmaxf(sv[0],sv[1]),fmaxf(sv[2],sv[3])),
                         fmaxf(fmaxf(sv[4],sv[5]),fmaxf(sv[6],sv[7])));
        float s8 = __expf(sv[0]-m8)+__expf(sv[1]-m8)+__expf(sv[2]-m8)+__expf(sv[3]-m8)
                 + __expf(sv[4]-m8)+__expf(sv[5]-m8)+__expf(sv[6]-m8)+__expf(sv[7]-m8);
        float M = fmaxf(sm[sidx], m8);
        ss[sidx] = ss[sidx]*__expf(sm[sidx]-M) + s8*__expf(m8-M);
        sm[sidx] = M;
        // all-masked group: m8=-1e30 => its terms get exp(-huge)=0 later; phantom s gated
        // at combine by M > -5e29 validity check.
      }
    }
  }

  // merge the 16 l15-lanes sharing each row, write per-(row,split) partial
#pragma unroll
  for (int sidx = 0; sidx < 8; sidx++){
    float mv = sm[sidx], sv2 = ss[sidx];
#pragma unroll
    for (int mask = 1; mask < 16; mask <<= 1){
      float m2 = __shfl_xor(mv, mask);
      float s2 = __shfl_xor(sv2, mask);
      float M = fmaxf(mv, m2);
      sv2 = sv2 * __expf(mv - M) + s2 * __expf(m2 - M);
      mv = M;
    }
    if (l15 == 0){
      int mt = sidx >> 2, rr = sidx & 3;
      int rl = w * 32 + mt * 16 + quad * 4 + rr;
      int o = split * B_N + i0 + rl;
      wsM[o] = mv; wsS[o] = sv2;
    }
  }
}

// ---------------- combine: merge splits, per-row loss ----------------
__global__ void combine_kernel(const float* __restrict__ wsM, const float* __restrict__ wsS,
                               const float* __restrict__ numer, const int* __restrict__ jsel,
                               float* __restrict__ per_row, unsigned* __restrict__ validc)
{
  int row = blockIdx.x * 256 + threadIdx.x;
  float M = -3.0e38f, S = 0.f;
  for (int p = 0; p < NSPLIT; p++){
    float m2 = wsM[p * B_N + row], s2 = wsS[p * B_N + row];
    float Mn = fmaxf(M, m2);
    S = S * __expf(M - Mn) + s2 * __expf(m2 - Mn);
    M = Mn;
  }
  bool v = (jsel[row] >= 0) && (M > -5e29f);
  per_row[row] = v ? (M + logf(S) - numer[row]) : 0.f;
  validc[row]  = v ? 1u : 0u;
}

__global__ void reduce_kernel(const float* __restrict__ per_row, const unsigned* __restrict__ validc,
                              float* __restrict__ out)
{
  int tid = threadIdx.x;
  float s = 0.f; unsigned n = 0u;
  for (int r = tid; r < B_N; r += 256){ s += per_row[r]; n += validc[r]; }
#pragma unroll
  for (int off = 32; off > 0; off >>= 1){ s += __shfl_down(s, off); n += __shfl_down(n, off); }
  __shared__ float ssm[4]; __shared__ unsigned snm[4];
  if ((tid & 63) == 0){ ssm[tid >> 6] = s; snm[tid >> 6] = n; }
  __syncthreads();
  if (tid == 0){
    float S = ssm[0] + ssm[1] + ssm[2] + ssm[3];
    unsigned N = snm[0] + snm[1] + snm[2] + snm[3];
    out[0] = (N > 0u) ? (S / (float)N) : 0.f;
  }
}

extern "C" void kernel_launch(void* const* d_in, const int* in_sizes, int n_in,
                              void* d_out, int out_size, void* d_ws, size_t ws_size,
                              hipStream_t stream)
{
  const float* E      = (const float*)d_in[0];
  const int*   labels = (const int*)d_in[1];
  float*       out    = (float*)d_out;

  ushort_t* Ebf  = (ushort_t*)d_ws;                       // 4 MB
  float* wsM     = (float*)(Ebf + (size_t)B_N * D_K);     // 256 KB
  float* wsS     = wsM + NSPLIT * B_N;                    // 256 KB
  float* sqb     = wsS + NSPLIT * B_N;                    // 32 KB
  float* numer   = sqb + B_N;                             // 32 KB
  float* per_row = numer + B_N;                           // 32 KB
  unsigned* validc = (unsigned*)(per_row + B_N);          // 32 KB
  int* jsel      = (int*)(validc + B_N);                  // 32 KB

  prep_kernel<<<B_N / 4, 256, 0, stream>>>(E, Ebf, sqb);
  sel_kernel<<<B_N / 4, 256, 0, stream>>>(labels, jsel, numer);
  fused_kernel<<<(B_N / BI) * NSPLIT, 256, 0, stream>>>(Ebf, labels, sqb, jsel, numer, wsM, wsS);
  combine_kernel<<<B_N / 256, 256, 0, stream>>>(wsM, wsS, numer, jsel, per_row, validc);
  reduce_kernel<<<1, 256, 0, stream>>>(per_row, validc, out);
}

// Round 4
// 197.545 us; speedup vs baseline: 3.9318x; 1.3619x over previous
//
#include <hip/hip_runtime.h>
#include <float.h>
#include <math.h>

// NPairLoss MI355X r4 = r3 with the wave-partial collision fixed:
// 2x2 wave grid means two waves (wx=0/1) share rows -> each gets its own
// partial slot (split*2+wx); combine folds 16 partials.
// prep -> memset+classify -> sel (bucketed gumbel + exact numerator) ->
// fused (MFMA gram 128x128) -> combine -> reduce.  ws ~5.8 MB.

#define B_N 8192
#define D_K 256
#define NCLS 100
#define MAXC 256
#define NSPLIT 8
#define NPART (NSPLIT * 2)     // 16 partials: (split, wx)
#define JR (B_N / NSPLIT)      // 1024
#define BI 128
#define BJ 128
#define NJT (JR / BJ)          // 8
#define BK 64
#define NKC (D_K / BK)         // 4
#define NEG_INF -1e30f

typedef __attribute__((ext_vector_type(8))) short bf16x8;
typedef __attribute__((ext_vector_type(4))) float f32x4;
typedef unsigned short ushort_t;

// ---------------- threefry2x32 / jax gumbel (bit-exact, known-good) ----------------
__device__ __forceinline__ unsigned rotl32(unsigned x, int d){ return (x << d) | (x >> (32 - d)); }

__device__ __forceinline__ float gumbel_at(unsigned idx){
  const unsigned HALF = (unsigned)B_N * (unsigned)B_N / 2u;
  unsigned c0, c1; bool second;
  if (idx < HALF){ c0 = idx; c1 = idx + HALF; second = false; }
  else            { c0 = idx - HALF; c1 = idx; second = true; }
  const unsigned ks0 = 0u, ks1 = 42u, ks2 = 0u ^ 42u ^ 0x1BD11BDAu;
  unsigned x0 = c0 + ks0, x1 = c1 + ks1;
#define TF_RND(r) { x0 += x1; x1 = rotl32(x1, (r)); x1 ^= x0; }
  TF_RND(13) TF_RND(15) TF_RND(26) TF_RND(6)   x0 += ks1; x1 += ks2 + 1u;
  TF_RND(17) TF_RND(29) TF_RND(16) TF_RND(24)  x0 += ks2; x1 += ks0 + 2u;
  TF_RND(13) TF_RND(15) TF_RND(26) TF_RND(6)   x0 += ks0; x1 += ks1 + 3u;
  TF_RND(17) TF_RND(29) TF_RND(16) TF_RND(24)  x0 += ks1; x1 += ks2 + 4u;
  TF_RND(13) TF_RND(15) TF_RND(26) TF_RND(6)   x0 += ks2; x1 += ks0 + 5u;
#undef TF_RND
  unsigned bits = second ? x1 : x0;
  float u = __uint_as_float((bits >> 9) | 0x3f800000u) - 1.0f;
  const float TINY = 1.17549435e-38f;
  u = u * (1.0f - TINY) + TINY;
  u = fmaxf(TINY, u);
  return -logf(-logf(u));
}

__device__ __forceinline__ ushort_t f2bf(float x){
  unsigned u = __float_as_uint(x);
  return (ushort_t)((u + 0x7FFFu + ((u >> 16) & 1u)) >> 16); // RNE
}

__device__ __forceinline__ void async16(const ushort_t* g, ushort_t* lds_wave_base){
  __builtin_amdgcn_global_load_lds((const __attribute__((address_space(1))) void*)g,
                                   (__attribute__((address_space(3))) void*)lds_wave_base,
                                   16, 0, 0);
}

// ---------------- prep: E fp32 -> bf16, sq[i] (exact fp32) ----------------
__global__ void prep_kernel(const float* __restrict__ E, ushort_t* __restrict__ Ebf,
                            float* __restrict__ sq){
  int w = threadIdx.x >> 6, lane = threadIdx.x & 63;
  int row = blockIdx.x * 4 + w;
  const float4 v = *reinterpret_cast<const float4*>(E + (size_t)row * D_K + lane * 4);
  float s = v.x*v.x + v.y*v.y + v.z*v.z + v.w*v.w;
#pragma unroll
  for (int off = 32; off > 0; off >>= 1) s += __shfl_down(s, off);
  if (lane == 0) sq[row] = s;
  ushort4 o; o.x = f2bf(v.x); o.y = f2bf(v.y); o.z = f2bf(v.z); o.w = f2bf(v.w);
  *reinterpret_cast<ushort4*>(Ebf + (size_t)row * D_K + lane * 4) = o;
}

// ---------------- classify: per-class member lists ----------------
__global__ void classify_kernel(const int* __restrict__ labels, int* __restrict__ cnt,
                                int* __restrict__ clist){
  int row = blockIdx.x * 256 + threadIdx.x;
  int lab = labels[row];
  int p = atomicAdd(&cnt[lab], 1);
  if (p < MAXC) clist[lab * MAXC + p] = row;
}

// ---------------- sel: gumbel-argmax over class members + exact fp32 numerator ----------------
__global__ void sel_kernel(const float* __restrict__ E, const int* __restrict__ labels,
                           const float* __restrict__ sq,
                           const int* __restrict__ cnt, const int* __restrict__ clist,
                           int* __restrict__ jsel, float* __restrict__ numer){
  int tid = threadIdx.x, w = tid >> 6, lane = tid & 63;
  int row = blockIdx.x * 4 + w;
  int li = labels[row];
  int n = min(cnt[li], MAXC);
  float gb = -FLT_MAX; int jb = 0x7FFFFFFF;
  for (int t = lane; t < n; t += 64){
    int j = clist[li * MAXC + t];
    if (j != row){
      float g = gumbel_at(((unsigned)row << 13) + (unsigned)j);
      if (g > gb || (g == gb && j < jb)){ gb = g; jb = j; }
    }
  }
#pragma unroll
  for (int mask = 1; mask < 64; mask <<= 1){
    float g2 = __shfl_xor(gb, mask);
    int   j2 = __shfl_xor(jb, mask);
    if (g2 > gb || (g2 == gb && j2 < jb)){ gb = g2; jb = j2; }
  }
  if (jb == 0x7FFFFFFF){
    if (lane == 0){ jsel[row] = -1; numer[row] = 0.f; }
    return;
  }
  // fp32-exact numerator: sim[row, jb]
  const float4 a = *reinterpret_cast<const float4*>(E + (size_t)row * D_K + lane * 4);
  const float4 b = *reinterpret_cast<const float4*>(E + (size_t)jb  * D_K + lane * 4);
  float d = a.x*b.x + a.y*b.y + a.z*b.z + a.w*b.w;
#pragma unroll
  for (int off = 32; off > 0; off >>= 1) d += __shfl_down(d, off);
  if (lane == 0){
    jsel[row] = jb;
    numer[row] = -10.f * fmaxf(sq[row] + sq[jb] - 2.f * d, 0.f);
  }
}

// ---------------- fused: MFMA gram + masked online-lse ----------------
__global__ __launch_bounds__(256, 3)
void fused_kernel(const ushort_t* __restrict__ Ebf, const int* __restrict__ labels,
                  const float* __restrict__ sq,
                  float* __restrict__ wsM, float* __restrict__ wsS)
{
  __shared__ __align__(16) ushort_t As[BI * BK];  // 16 KB, XOR-swizzled 16B groups
  __shared__ __align__(16) ushort_t Bs[BJ * BK];  // 16 KB
  __shared__ float s_sqj[JR];   // 4 KB
  __shared__ int   s_lj[JR];    // 4 KB
  __shared__ float s_sqi[BI];
  __shared__ int   s_li[BI];

  const int bi    = blockIdx.x >> 3;
  const int split = blockIdx.x & 7;
  const int i0    = bi * BI;
  const int jbase = split * JR;
  const int tid   = threadIdx.x;
  const int lane  = tid & 63;
  const int w     = tid >> 6;
  const int wy    = w >> 1;
  const int wx    = w & 1;
  const int quad  = lane >> 4;
  const int l15   = lane & 15;

  for (int t = tid; t < JR; t += 256){ s_sqj[t] = sq[jbase + t]; s_lj[t] = labels[jbase + t]; }
  if (tid < BI){ s_sqi[tid] = sq[i0 + tid]; s_li[tid] = labels[i0 + tid]; }

  float sm[16], ssum[16];
#pragma unroll
  for (int r = 0; r < 16; r++){ sm[r] = NEG_INF; ssum[r] = 0.f; }

  for (int jt = 0; jt < NJT; jt++){
    const int j0 = jbase + jt * BJ;
    f32x4 acc[4][4];
#pragma unroll
    for (int mt = 0; mt < 4; mt++)
#pragma unroll
      for (int nt = 0; nt < 4; nt++) acc[mt][nt] = (f32x4)0.f;

    for (int kc = 0; kc < NKC; kc++){
      const int koff = kc * BK;
      __syncthreads();
#pragma unroll
      for (int rd = 0; rd < 4; rd++){
        int slot = rd * 256 + tid;            // 16B slot: row = slot>>3, stored group = slot&7
        int r = slot >> 3, gs = slot & 7;
        int gsrc = (gs ^ (r & 7)) << 3;       // swizzle applied on global gather side
        ushort_t* ldsA = As + (size_t)(rd * 256 + w * 64) * 8;
        ushort_t* ldsB = Bs + (size_t)(rd * 256 + w * 64) * 8;
        async16(Ebf + (size_t)(i0 + r) * D_K + koff + gsrc, ldsA);
        async16(Ebf + (size_t)(j0 + r) * D_K + koff + gsrc, ldsB);
      }
      __syncthreads();
#pragma unroll
      for (int s = 0; s < 2; s++){
        int g = s * 4 + quad;
        bf16x8 af[4], bfr[4];
#pragma unroll
        for (int mt = 0; mt < 4; mt++){
          int r = wy * 64 + mt * 16 + l15;
          af[mt] = *reinterpret_cast<const bf16x8*>(&As[r * BK + ((g ^ (r & 7)) << 3)]);
        }
#pragma unroll
        for (int nt = 0; nt < 4; nt++){
          int r = wx * 64 + nt * 16 + l15;
          bfr[nt] = *reinterpret_cast<const bf16x8*>(&Bs[r * BK + ((g ^ (r & 7)) << 3)]);
        }
#pragma unroll
        for (int mt = 0; mt < 4; mt++)
#pragma unroll
          for (int nt = 0; nt < 4; nt++)
            acc[mt][nt] = __builtin_amdgcn_mfma_f32_16x16x32_bf16(af[mt], bfr[nt], acc[mt][nt], 0, 0, 0);
      }
      __syncthreads();
    }

    // ---- epilogue for this 128x128 tile ----
    float sqj[4]; int lj[4];
#pragma unroll
    for (int nt = 0; nt < 4; nt++){
      int c = jt * BJ + wx * 64 + nt * 16 + l15;
      sqj[nt] = s_sqj[c]; lj[nt] = s_lj[c];
    }
#pragma unroll
    for (int mt = 0; mt < 4; mt++){
#pragma unroll
      for (int rr = 0; rr < 4; rr++){
        int rl = wy * 64 + mt * 16 + quad * 4 + rr;   // C/D: row = quad*4+reg, col = l15
        float sqv = s_sqi[rl]; int lrow = s_li[rl];
        int sidx = mt * 4 + rr;
        float sv[4];
#pragma unroll
        for (int nt = 0; nt < 4; nt++){
          float a = acc[mt][nt][rr];
          float simv = -10.f * fmaxf(fmaf(-2.f, a, sqv + sqj[nt]), 0.f);
          sv[nt] = (lj[nt] != lrow) ? simv : NEG_INF;  // masks positives + same-label + diag
        }
        float m4 = fmaxf(fmaxf(sv[0], sv[1]), fmaxf(sv[2], sv[3]));
        float s4 = __expf(sv[0]-m4) + __expf(sv[1]-m4) + __expf(sv[2]-m4) + __expf(sv[3]-m4);
        float M = fmaxf(sm[sidx], m4);
        ssum[sidx] = ssum[sidx]*__expf(sm[sidx]-M) + s4*__expf(m4-M);
        sm[sidx] = M;
      }
    }
  }

  // merge the 16 l15-lanes sharing each row; one write per (row, split, wx).
  // NOTE: waves with the same wy but different wx hold partials for the SAME rows
  // over different column halves -> each (split, wx) gets its own partial slot.
#pragma unroll
  for (int sidx = 0; sidx < 16; sidx++){
    float mv = sm[sidx], sv2 = ssum[sidx];
#pragma unroll
    for (int mask = 1; mask < 16; mask <<= 1){
      float m2 = __shfl_xor(mv, mask);
      float s2 = __shfl_xor(sv2, mask);
      float M = fmaxf(mv, m2);
      sv2 = sv2 * __expf(mv - M) + s2 * __expf(m2 - M);
      mv = M;
    }
    if (l15 == 0){
      int mt = sidx >> 2, rr = sidx & 3;
      int rl = wy * 64 + mt * 16 + quad * 4 + rr;
      int o = (split * 2 + wx) * B_N + i0 + rl;
      wsM[o] = mv; wsS[o] = sv2;
    }
  }
}

// ---------------- combine / reduce ----------------
__global__ void combine_kernel(const float* __restrict__ wsM, const float* __restrict__ wsS,
                               const float* __restrict__ numer, const int* __restrict__ jsel,
                               float* __restrict__ per_row, unsigned* __restrict__ validc)
{
  int row = blockIdx.x * 256 + threadIdx.x;
  float M = -3.0e38f, S = 0.f;
  for (int p = 0; p < NPART; p++){
    float m2 = wsM[p * B_N + row], s2 = wsS[p * B_N + row];
    float Mn = fmaxf(M, m2);
    S = S * __expf(M - Mn) + s2 * __expf(m2 - Mn);
    M = Mn;
  }
  bool v = (jsel[row] >= 0) && (M > -5e29f);
  per_row[row] = v ? (M + logf(S) - numer[row]) : 0.f;
  validc[row]  = v ? 1u : 0u;
}

__global__ void reduce_kernel(const float* __restrict__ per_row, const unsigned* __restrict__ validc,
                              float* __restrict__ out)
{
  int tid = threadIdx.x;
  float s = 0.f; unsigned n = 0u;
  for (int r = tid; r < B_N; r += 256){ s += per_row[r]; n += validc[r]; }
#pragma unroll
  for (int off = 32; off > 0; off >>= 1){ s += __shfl_down(s, off); n += __shfl_down(n, off); }
  __shared__ float ssm[4]; __shared__ unsigned snm[4];
  if ((tid & 63) == 0){ ssm[tid >> 6] = s; snm[tid >> 6] = n; }
  __syncthreads();
  if (tid == 0){
    float S = ssm[0] + ssm[1] + ssm[2] + ssm[3];
    unsigned N = snm[0] + snm[1] + snm[2] + snm[3];
    out[0] = (N > 0u) ? (S / (float)N) : 0.f;
  }
}

extern "C" void kernel_launch(void* const* d_in, const int* in_sizes, int n_in,
                              void* d_out, int out_size, void* d_ws, size_t ws_size,
                              hipStream_t stream)
{
  const float* E      = (const float*)d_in[0];
  const int*   labels = (const int*)d_in[1];
  float*       out    = (float*)d_out;

  ushort_t* Ebf    = (ushort_t*)d_ws;                     // 4 MB
  float* wsM       = (float*)(Ebf + (size_t)B_N * D_K);   // 512 KB (16 partials)
  float* wsS       = wsM + NPART * B_N;                   // 512 KB
  float* sqb       = wsS + NPART * B_N;                   // 32 KB
  float* numer     = sqb + B_N;                           // 32 KB
  float* per_row   = numer + B_N;                         // 32 KB
  unsigned* validc = (unsigned*)(per_row + B_N);          // 32 KB
  int* jsel        = (int*)(validc + B_N);                // 32 KB
  int* cnt         = jsel + B_N;                          // 400 B
  int* clist       = cnt + NCLS;                          // 100 KB

  hipMemsetAsync(cnt, 0, NCLS * sizeof(int), stream);
  prep_kernel<<<B_N / 4, 256, 0, stream>>>(E, Ebf, sqb);
  classify_kernel<<<B_N / 256, 256, 0, stream>>>(labels, cnt, clist);
  sel_kernel<<<B_N / 4, 256, 0, stream>>>(E, labels, sqb, cnt, clist, jsel, numer);
  fused_kernel<<<(B_N / BI) * NSPLIT, 256, 0, stream>>>(Ebf, labels, sqb, wsM, wsS);
  combine_kernel<<<B_N / 256, 256, 0, stream>>>(wsM, wsS, numer, jsel, per_row, validc);
  reduce_kernel<<<1, 256, 0, stream>>>(per_row, validc, out);
}

// Round 5
// 168.187 us; speedup vs baseline: 4.6181x; 1.1746x over previous
//
#include <hip/hip_runtime.h>
#include <float.h>
#include <math.h>

// NPairLoss MI355X r5: A register-resident MFMA gram.
// Each wave holds 32 A-rows x K=256 as MFMA fragments in VGPRs (loaded once);
// K-loop stages only B tiles into LDS (16KB chunks) -> half the LDS reads,
// ~40% less staging traffic vs r4. NSPLIT=16 for 1024 blocks (occupancy).
// prep -> memset+classify -> sel -> fused -> combine -> reduce.  ws ~5.8 MB.

#define B_N 8192
#define D_K 256
#define NCLS 100
#define MAXC 256
#define NSPLIT 16
#define NPART NSPLIT
#define JR (B_N / NSPLIT)      // 512
#define BI 128
#define BJ 128
#define NJT (JR / BJ)          // 4
#define BK 64
#define NKC (D_K / BK)         // 4
#define NEG_INF -1e30f

typedef __attribute__((ext_vector_type(8))) short bf16x8;
typedef __attribute__((ext_vector_type(4))) float f32x4;
typedef unsigned short ushort_t;

// ---------------- threefry2x32 / jax gumbel (bit-exact, known-good) ----------------
__device__ __forceinline__ unsigned rotl32(unsigned x, int d){ return (x << d) | (x >> (32 - d)); }

__device__ __forceinline__ float gumbel_at(unsigned idx){
  const unsigned HALF = (unsigned)B_N * (unsigned)B_N / 2u;
  unsigned c0, c1; bool second;
  if (idx < HALF){ c0 = idx; c1 = idx + HALF; second = false; }
  else            { c0 = idx - HALF; c1 = idx; second = true; }
  const unsigned ks0 = 0u, ks1 = 42u, ks2 = 0u ^ 42u ^ 0x1BD11BDAu;
  unsigned x0 = c0 + ks0, x1 = c1 + ks1;
#define TF_RND(r) { x0 += x1; x1 = rotl32(x1, (r)); x1 ^= x0; }
  TF_RND(13) TF_RND(15) TF_RND(26) TF_RND(6)   x0 += ks1; x1 += ks2 + 1u;
  TF_RND(17) TF_RND(29) TF_RND(16) TF_RND(24)  x0 += ks2; x1 += ks0 + 2u;
  TF_RND(13) TF_RND(15) TF_RND(26) TF_RND(6)   x0 += ks0; x1 += ks1 + 3u;
  TF_RND(17) TF_RND(29) TF_RND(16) TF_RND(24)  x0 += ks1; x1 += ks2 + 4u;
  TF_RND(13) TF_RND(15) TF_RND(26) TF_RND(6)   x0 += ks2; x1 += ks0 + 5u;
#undef TF_RND
  unsigned bits = second ? x1 : x0;
  float u = __uint_as_float((bits >> 9) | 0x3f800000u) - 1.0f;
  const float TINY = 1.17549435e-38f;
  u = u * (1.0f - TINY) + TINY;
  u = fmaxf(TINY, u);
  return -logf(-logf(u));
}

__device__ __forceinline__ ushort_t f2bf(float x){
  unsigned u = __float_as_uint(x);
  return (ushort_t)((u + 0x7FFFu + ((u >> 16) & 1u)) >> 16); // RNE
}

__device__ __forceinline__ void async16(const ushort_t* g, ushort_t* lds_wave_base){
  __builtin_amdgcn_global_load_lds((const __attribute__((address_space(1))) void*)g,
                                   (__attribute__((address_space(3))) void*)lds_wave_base,
                                   16, 0, 0);
}

// ---------------- prep: E fp32 -> bf16, sq[i] (exact fp32) ----------------
__global__ void prep_kernel(const float* __restrict__ E, ushort_t* __restrict__ Ebf,
                            float* __restrict__ sq){
  int w = threadIdx.x >> 6, lane = threadIdx.x & 63;
  int row = blockIdx.x * 4 + w;
  const float4 v = *reinterpret_cast<const float4*>(E + (size_t)row * D_K + lane * 4);
  float s = v.x*v.x + v.y*v.y + v.z*v.z + v.w*v.w;
#pragma unroll
  for (int off = 32; off > 0; off >>= 1) s += __shfl_down(s, off);
  if (lane == 0) sq[row] = s;
  ushort4 o; o.x = f2bf(v.x); o.y = f2bf(v.y); o.z = f2bf(v.z); o.w = f2bf(v.w);
  *reinterpret_cast<ushort4*>(Ebf + (size_t)row * D_K + lane * 4) = o;
}

// ---------------- classify: per-class member lists ----------------
__global__ void classify_kernel(const int* __restrict__ labels, int* __restrict__ cnt,
                                int* __restrict__ clist){
  int row = blockIdx.x * 256 + threadIdx.x;
  int lab = labels[row];
  int p = atomicAdd(&cnt[lab], 1);
  if (p < MAXC) clist[lab * MAXC + p] = row;
}

// ---------------- sel: gumbel-argmax over class members + exact fp32 numerator ----------------
__global__ void sel_kernel(const float* __restrict__ E, const int* __restrict__ labels,
                           const float* __restrict__ sq,
                           const int* __restrict__ cnt, const int* __restrict__ clist,
                           int* __restrict__ jsel, float* __restrict__ numer){
  int tid = threadIdx.x, w = tid >> 6, lane = tid & 63;
  int row = blockIdx.x * 4 + w;
  int li = labels[row];
  int n = min(cnt[li], MAXC);
  float gb = -FLT_MAX; int jb = 0x7FFFFFFF;
  for (int t = lane; t < n; t += 64){
    int j = clist[li * MAXC + t];
    if (j != row){
      float g = gumbel_at(((unsigned)row << 13) + (unsigned)j);
      if (g > gb || (g == gb && j < jb)){ gb = g; jb = j; }
    }
  }
#pragma unroll
  for (int mask = 1; mask < 64; mask <<= 1){
    float g2 = __shfl_xor(gb, mask);
    int   j2 = __shfl_xor(jb, mask);
    if (g2 > gb || (g2 == gb && j2 < jb)){ gb = g2; jb = j2; }
  }
  if (jb == 0x7FFFFFFF){
    if (lane == 0){ jsel[row] = -1; numer[row] = 0.f; }
    return;
  }
  const float4 a = *reinterpret_cast<const float4*>(E + (size_t)row * D_K + lane * 4);
  const float4 b = *reinterpret_cast<const float4*>(E + (size_t)jb  * D_K + lane * 4);
  float d = a.x*b.x + a.y*b.y + a.z*b.z + a.w*b.w;
#pragma unroll
  for (int off = 32; off > 0; off >>= 1) d += __shfl_down(d, off);
  if (lane == 0){
    jsel[row] = jb;
    numer[row] = -10.f * fmaxf(sq[row] + sq[jb] - 2.f * d, 0.f);
  }
}

// ---------------- fused: A-resident MFMA gram + masked online-lse ----------------
__global__ __launch_bounds__(256, 3)
void fused_kernel(const ushort_t* __restrict__ Ebf, const int* __restrict__ labels,
                  const float* __restrict__ sq,
                  float* __restrict__ wsM, float* __restrict__ wsS)
{
  __shared__ __align__(16) ushort_t Bs[BJ * BK];  // 16 KB, XOR-swizzled 16B groups
  __shared__ float s_sqj[JR];   // 2 KB
  __shared__ int   s_lj[JR];    // 2 KB
  __shared__ float s_sqi[BI];
  __shared__ int   s_li[BI];

  const int bi    = blockIdx.x >> 4;         // 0..63
  const int split = blockIdx.x & 15;         // 0..15
  const int i0    = bi * BI;
  const int jbase = split * JR;
  const int tid   = threadIdx.x;
  const int lane  = tid & 63;
  const int w     = tid >> 6;                // wave 0..3, owns rows [w*32, w*32+32)
  const int quad  = lane >> 4;
  const int l15   = lane & 15;

  for (int t = tid; t < JR; t += 256){ s_sqj[t] = sq[jbase + t]; s_lj[t] = labels[jbase + t]; }
  if (tid < BI){ s_sqi[tid] = sq[i0 + tid]; s_li[tid] = labels[i0 + tid]; }

  // A fragments: wave's 32 rows x K=256, register-resident. af[mt][c]:
  // rows w*32 + mt*16 + l15, k = c*32 + quad*8 + (0..7)  (16B contiguous per lane).
  bf16x8 af[2][8];
#pragma unroll
  for (int mt = 0; mt < 2; mt++){
    const ushort_t* rp = Ebf + (size_t)(i0 + w * 32 + mt * 16 + l15) * D_K + quad * 8;
#pragma unroll
    for (int c = 0; c < 8; c++)
      af[mt][c] = *reinterpret_cast<const bf16x8*>(rp + c * 32);
  }

  float sm[8], ssum[8];
#pragma unroll
  for (int r = 0; r < 8; r++){ sm[r] = NEG_INF; ssum[r] = 0.f; }

  __syncthreads();  // s_sqj/s_lj ready

  for (int jt = 0; jt < NJT; jt++){
    const int j0 = jbase + jt * BJ;
    f32x4 acc[2][8];
#pragma unroll
    for (int mt = 0; mt < 2; mt++)
#pragma unroll
      for (int nt = 0; nt < 8; nt++) acc[mt][nt] = (f32x4)0.f;

    for (int kc = 0; kc < NKC; kc++){
      const int koff = kc * BK;
      __syncthreads();                       // protect Bs from previous consumers
#pragma unroll
      for (int rd = 0; rd < 4; rd++){
        int slot = rd * 256 + tid;           // 1024 slots of 16B: row = slot>>3, group = slot&7
        int r = slot >> 3, gs = slot & 7;
        int gsrc = (gs ^ (r & 7)) << 3;      // swizzle on the gather side
        ushort_t* ldsB = Bs + (size_t)(rd * 256 + w * 64) * 8;
        async16(Ebf + (size_t)(j0 + r) * D_K + koff + gsrc, ldsB);
      }
      __syncthreads();                       // staged (vmcnt drained before barrier)
#pragma unroll
      for (int s = 0; s < 2; s++){
        const int g = s * 4 + quad;          // k-group within 64-chunk
        const int c = kc * 2 + s;            // global 32-k chunk index for A frags
        bf16x8 bfr[8];
#pragma unroll
        for (int nt = 0; nt < 8; nt++){
          int r = nt * 16 + l15;
          bfr[nt] = *reinterpret_cast<const bf16x8*>(&Bs[r * BK + ((g ^ (r & 7)) << 3)]);
        }
#pragma unroll
        for (int nt = 0; nt < 8; nt++){
          acc[0][nt] = __builtin_amdgcn_mfma_f32_16x16x32_bf16(af[0][c], bfr[nt], acc[0][nt], 0, 0, 0);
          acc[1][nt] = __builtin_amdgcn_mfma_f32_16x16x32_bf16(af[1][c], bfr[nt], acc[1][nt], 0, 0, 0);
        }
      }
    }

    // ---- epilogue for this 128-col tile (wave-exclusive rows) ----
    float sqj[8]; int lj[8];
#pragma unroll
    for (int nt = 0; nt < 8; nt++){
      int ccol = jt * BJ + nt * 16 + l15;
      sqj[nt] = s_sqj[ccol]; lj[nt] = s_lj[ccol];
    }
#pragma unroll
    for (int mt = 0; mt < 2; mt++){
#pragma unroll
      for (int rr = 0; rr < 4; rr++){
        int rl = w * 32 + mt * 16 + quad * 4 + rr;   // C/D: row = quad*4+reg, col = l15
        float sqv = s_sqi[rl]; int lrow = s_li[rl];
        int sidx = mt * 4 + rr;
        float sv[8];
#pragma unroll
        for (int nt = 0; nt < 8; nt++){
          float a = acc[mt][nt][rr];
          float simv = -10.f * fmaxf(fmaf(-2.f, a, sqv + sqj[nt]), 0.f);
          sv[nt] = (lj[nt] != lrow) ? simv : NEG_INF;  // masks positives + same-label + diag
        }
        float m8 = fmaxf(fmaxf(fmaxf(sv[0],sv[1]),fmaxf(sv[2],sv[3])),
                         fmaxf(fmaxf(sv[4],sv[5]),fmaxf(sv[6],sv[7])));
        float s8 = __expf(sv[0]-m8)+__expf(sv[1]-m8)+__expf(sv[2]-m8)+__expf(sv[3]-m8)
                 + __expf(sv[4]-m8)+__expf(sv[5]-m8)+__expf(sv[6]-m8)+__expf(sv[7]-m8);
        float M = fmaxf(sm[sidx], m8);
        ssum[sidx] = ssum[sidx]*__expf(sm[sidx]-M) + s8*__expf(m8-M);
        sm[sidx] = M;
      }
    }
  }

  // merge the 16 l15-lanes sharing each row; rows are wave-exclusive -> one slot per split
#pragma unroll
  for (int sidx = 0; sidx < 8; sidx++){
    float mv = sm[sidx], sv2 = ssum[sidx];
#pragma unroll
    for (int mask = 1; mask < 16; mask <<= 1){
      float m2 = __shfl_xor(mv, mask);
      float s2 = __shfl_xor(sv2, mask);
      float M = fmaxf(mv, m2);
      sv2 = sv2 * __expf(mv - M) + s2 * __expf(m2 - M);
      mv = M;
    }
    if (l15 == 0){
      int mt = sidx >> 2, rr = sidx & 3;
      int rl = w * 32 + mt * 16 + quad * 4 + rr;
      int o = split * B_N + i0 + rl;
      wsM[o] = mv; wsS[o] = sv2;
    }
  }
}

// ---------------- combine / reduce ----------------
__global__ void combine_kernel(const float* __restrict__ wsM, const float* __restrict__ wsS,
                               const float* __restrict__ numer, const int* __restrict__ jsel,
                               float* __restrict__ per_row, unsigned* __restrict__ validc)
{
  int row = blockIdx.x * 256 + threadIdx.x;
  float M = -3.0e38f, S = 0.f;
  for (int p = 0; p < NPART; p++){
    float m2 = wsM[p * B_N + row], s2 = wsS[p * B_N + row];
    float Mn = fmaxf(M, m2);
    S = S * __expf(M - Mn) + s2 * __expf(m2 - Mn);
    M = Mn;
  }
  bool v = (jsel[row] >= 0) && (M > -5e29f);
  per_row[row] = v ? (M + logf(S) - numer[row]) : 0.f;
  validc[row]  = v ? 1u : 0u;
}

__global__ void reduce_kernel(const float* __restrict__ per_row, const unsigned* __restrict__ validc,
                              float* __restrict__ out)
{
  int tid = threadIdx.x;
  float s = 0.f; unsigned n = 0u;
  for (int r = tid; r < B_N; r += 256){ s += per_row[r]; n += validc[r]; }
#pragma unroll
  for (int off = 32; off > 0; off >>= 1){ s += __shfl_down(s, off); n += __shfl_down(n, off); }
  __shared__ float ssm[4]; __shared__ unsigned snm[4];
  if ((tid & 63) == 0){ ssm[tid >> 6] = s; snm[tid >> 6] = n; }
  __syncthreads();
  if (tid == 0){
    float S = ssm[0] + ssm[1] + ssm[2] + ssm[3];
    unsigned N = snm[0] + snm[1] + snm[2] + snm[3];
    out[0] = (N > 0u) ? (S / (float)N) : 0.f;
  }
}

extern "C" void kernel_launch(void* const* d_in, const int* in_sizes, int n_in,
                              void* d_out, int out_size, void* d_ws, size_t ws_size,
                              hipStream_t stream)
{
  const float* E      = (const float*)d_in[0];
  const int*   labels = (const int*)d_in[1];
  float*       out    = (float*)d_out;

  ushort_t* Ebf    = (ushort_t*)d_ws;                     // 4 MB
  float* wsM       = (float*)(Ebf + (size_t)B_N * D_K);   // 512 KB (16 partials)
  float* wsS       = wsM + NPART * B_N;                   // 512 KB
  float* sqb       = wsS + NPART * B_N;                   // 32 KB
  float* numer     = sqb + B_N;                           // 32 KB
  float* per_row   = numer + B_N;                         // 32 KB
  unsigned* validc = (unsigned*)(per_row + B_N);          // 32 KB
  int* jsel        = (int*)(validc + B_N);                // 32 KB
  int* cnt         = jsel + B_N;                          // 400 B
  int* clist       = cnt + NCLS;                          // 100 KB

  hipMemsetAsync(cnt, 0, NCLS * sizeof(int), stream);
  prep_kernel<<<B_N / 4, 256, 0, stream>>>(E, Ebf, sqb);
  classify_kernel<<<B_N / 256, 256, 0, stream>>>(labels, cnt, clist);
  sel_kernel<<<B_N / 4, 256, 0, stream>>>(E, labels, sqb, cnt, clist, jsel, numer);
  fused_kernel<<<(B_N / BI) * NSPLIT, 256, 0, stream>>>(Ebf, labels, sqb, wsM, wsS);
  combine_kernel<<<B_N / 256, 256, 0, stream>>>(wsM, wsS, numer, jsel, per_row, validc);
  reduce_kernel<<<1, 256, 0, stream>>>(per_row, validc, out);
}